// Round 1
// baseline (447.331 us; speedup 1.0000x reference)
//
#include <hip/hip_runtime.h>
#include <hip/hip_bf16.h>

// HoloAttention: out = (Re(cumsum_t(x@Wv^T * e^{i t f}) * e^{-i t f})) @ Wo^T
// (k-projection in reference is dead code — skipped.)
//
// Pipeline:
//  1. cast x, Wv, Wo to bf16 (ws)
//  2. GEMM1 (bf16 MFMA): v = x@Wv^T  -> fp32, stored in d_out (reused scratch)
//  3. blocked complex scan over t (64 chunks x 128):
//     pass1: per-chunk complex sums; pass2: exclusive prefix of chunk sums;
//     pass3: replay chunk, unbind with conj rotor, write retrieved as bf16
//  4. GEMM2 (bf16 MFMA): out = retrieved@Wo^T -> fp32 d_out

#define B_  2
#define T_  8192
#define D_  1024
#define BT_ 16384
#define CS_ 128
#define NCHUNK_ 64

typedef __attribute__((ext_vector_type(4))) float f32x4;
typedef __attribute__((ext_vector_type(8))) short bf16x8;

static __device__ inline unsigned short f2bf(float f) {
    union { float f; unsigned int u; } a;
    a.f = f;
    unsigned int u = a.u;
    unsigned int r = (u + 0x7FFFu + ((u >> 16) & 1u)) >> 16;  // RNE
    return (unsigned short)r;
}

__global__ __launch_bounds__(256) void cast_f32_bf16(const float* __restrict__ in,
                                                     unsigned short* __restrict__ out, int n4) {
    int i = blockIdx.x * 256 + threadIdx.x;
    if (i < n4) {
        float4 v = ((const float4*)in)[i];
        ushort4 o;
        o.x = f2bf(v.x); o.y = f2bf(v.y); o.z = f2bf(v.z); o.w = f2bf(v.w);
        ((ushort4*)out)[i] = o;
    }
}

// C[M,N] = A[M,K] (bf16, row-major) @ Bm[N,K]^T (bf16, row-major), fp32 out.
// Block = 4 waves (2x2), wave tile 64x64 (4x4 mfma 16x16x32), block tile 128x128.
__global__ __launch_bounds__(256) void gemm_bt(const short* __restrict__ A,
                                               const short* __restrict__ Bm,
                                               float* __restrict__ C,
                                               int M, int N, int K) {
    const int lane = threadIdx.x & 63;
    const int wave = threadIdx.x >> 6;
    const int wr = wave >> 1, wc = wave & 1;
    const int bm = blockIdx.y * 128, bn = blockIdx.x * 128;
    const int m_base = bm + wr * 64 + (lane & 15);
    const int n_base = bn + wc * 64 + (lane & 15);
    const int k_off = (lane >> 4) * 8;

    f32x4 acc[4][4] = {};

    for (int k0 = 0; k0 < K; k0 += 32) {
        const int kk = k0 + k_off;
        bf16x8 a[4], b[4];
#pragma unroll
        for (int i = 0; i < 4; ++i)
            a[i] = *(const bf16x8*)(A + (size_t)(m_base + i * 16) * K + kk);
#pragma unroll
        for (int j = 0; j < 4; ++j)
            b[j] = *(const bf16x8*)(Bm + (size_t)(n_base + j * 16) * K + kk);
#pragma unroll
        for (int i = 0; i < 4; ++i)
#pragma unroll
            for (int j = 0; j < 4; ++j)
                acc[i][j] = __builtin_amdgcn_mfma_f32_16x16x32_bf16(a[i], b[j], acc[i][j], 0, 0, 0);
    }

    const int row0 = (lane >> 4) * 4;
#pragma unroll
    for (int i = 0; i < 4; ++i) {
#pragma unroll
        for (int j = 0; j < 4; ++j) {
            const int col = bn + wc * 64 + j * 16 + (lane & 15);
#pragma unroll
            for (int r = 0; r < 4; ++r) {
                const int row = bm + wr * 64 + i * 16 + row0 + r;
                C[(size_t)row * N + col] = acc[i][j][r];
            }
        }
    }
}

// Pass 1: per-chunk complex sums of w_t = v_t * e^{i t f}
__global__ __launch_bounds__(256) void scan_pass1(const float* __restrict__ v,
                                                  const float* __restrict__ freqs,
                                                  float* __restrict__ csum) {
    const int d = blockIdx.x * 256 + threadIdx.x;
    const int chunk = blockIdx.y;
    const int b = blockIdx.z;
    const float f = freqs[d];
    float ar = 0.f, ai = 0.f;
    const int t0 = chunk * CS_;
    const float* vp = v + ((size_t)b * T_ + t0) * D_ + d;
    for (int t = t0; t < t0 + CS_; ++t) {
        float w = *vp; vp += D_;
        float p = (float)t * f;   // fp32 phase, same as numpy
        float s, c;
        sincosf(p, &s, &c);
        ar += w * c; ai += w * s;
    }
    const size_t idx = (((size_t)b * NCHUNK_ + chunk) * D_ + d) * 2;
    csum[idx] = ar; csum[idx + 1] = ai;
}

// Pass 2: in-place exclusive prefix of chunk sums per (b,d)
__global__ __launch_bounds__(256) void scan_pass2(float* __restrict__ csum) {
    const int g = blockIdx.x * 256 + threadIdx.x;  // 0 .. B*D-1
    const int b = g / D_;
    const int d = g % D_;
    float pr = 0.f, pi = 0.f;
    for (int chunk = 0; chunk < NCHUNK_; ++chunk) {
        const size_t idx = (((size_t)b * NCHUNK_ + chunk) * D_ + d) * 2;
        float r = csum[idx], im = csum[idx + 1];
        csum[idx] = pr; csum[idx + 1] = pi;
        pr += r; pi += im;
    }
}

// Pass 3: replay chunk with prefix offset; retrieved = Re(mt * conj(rotor)) -> bf16
__global__ __launch_bounds__(256) void scan_pass3(const float* __restrict__ v,
                                                  const float* __restrict__ freqs,
                                                  const float* __restrict__ csum,
                                                  unsigned short* __restrict__ ret) {
    const int d = blockIdx.x * 256 + threadIdx.x;
    const int chunk = blockIdx.y;
    const int b = blockIdx.z;
    const float f = freqs[d];
    const size_t cidx = (((size_t)b * NCHUNK_ + chunk) * D_ + d) * 2;
    float ar = csum[cidx], ai = csum[cidx + 1];
    const int t0 = chunk * CS_;
    const float* vp = v + ((size_t)b * T_ + t0) * D_ + d;
    unsigned short* rp = ret + ((size_t)b * T_ + t0) * D_ + d;
    for (int t = t0; t < t0 + CS_; ++t) {
        float w = *vp; vp += D_;
        float p = (float)t * f;
        float s, c;
        sincosf(p, &s, &c);
        ar += w * c; ai += w * s;
        float o = ar * c + ai * s;   // Re(mt * (cos - i sin))
        *rp = f2bf(o); rp += D_;
    }
}

extern "C" void kernel_launch(void* const* d_in, const int* in_sizes, int n_in,
                              void* d_out, int out_size, void* d_ws, size_t ws_size,
                              hipStream_t stream) {
    const float* x     = (const float*)d_in[0];
    // d_in[1] = Wk (dead in reference — never used downstream)
    const float* Wv    = (const float*)d_in[2];
    const float* Wo    = (const float*)d_in[3];
    const float* freqs = (const float*)d_in[4];
    float* out = (float*)d_out;

    char* ws = (char*)d_ws;
    unsigned short* x_bf  = (unsigned short*)ws;                      // 33,554,432 B
    unsigned short* Wv_bf = (unsigned short*)(ws + 33554432);         //  2,097,152 B
    unsigned short* Wo_bf = (unsigned short*)(ws + 35651584);         //  2,097,152 B
    float*          csum  = (float*)(ws + 37748736);                  //  1,048,576 B
    unsigned short* ret   = (unsigned short*)(ws + 38797312);         // 33,554,432 B
    float* v = out;  // reuse d_out as fp32 scratch for v (overwritten by GEMM2)

    // 1. casts
    cast_f32_bf16<<<(BT_ * D_ / 4 + 255) / 256, 256, 0, stream>>>(x, x_bf, BT_ * D_ / 4);
    cast_f32_bf16<<<(D_ * D_ / 4 + 255) / 256, 256, 0, stream>>>(Wv, Wv_bf, D_ * D_ / 4);
    cast_f32_bf16<<<(D_ * D_ / 4 + 255) / 256, 256, 0, stream>>>(Wo, Wo_bf, D_ * D_ / 4);

    // 2. v = x @ Wv^T
    gemm_bt<<<dim3(D_ / 128, BT_ / 128), 256, 0, stream>>>((const short*)x_bf, (const short*)Wv_bf, v, BT_, D_, D_);

    // 3. blocked rotor scan
    dim3 sgrid(D_ / 256, NCHUNK_, B_);
    scan_pass1<<<sgrid, 256, 0, stream>>>(v, freqs, csum);
    scan_pass2<<<(B_ * D_) / 256, 256, 0, stream>>>(csum);
    scan_pass3<<<sgrid, 256, 0, stream>>>(v, freqs, csum, ret);

    // 4. out = retrieved @ Wo^T
    gemm_bt<<<dim3(D_ / 128, BT_ / 128), 256, 0, stream>>>((const short*)ret, (const short*)Wo_bf, out, BT_, D_, D_);
}

// Round 2
// 278.991 us; speedup vs baseline: 1.6034x; 1.6034x over previous
//
#include <hip/hip_runtime.h>
#include <hip/hip_bf16.h>

// HoloAttention: out = (Re(cumsum_t(x@Wv^T * e^{i t f}) * e^{-i t f})) @ Wo^T
// (k-projection in reference is dead code — skipped.)
//
// R2: m97-structure GEMM (global_load_lds width=16, 128x128 tile, 2-barrier
// K-loop), incremental-rotor scan (1 sincosf pair per 64-chunk), bf16 v
// stored in d_out's first half.

#define B_  2
#define T_  8192
#define D_  1024
#define BT_ 16384
#define CS_ 64
#define NCHUNK_ 128

typedef __attribute__((ext_vector_type(4))) float f32x4;
typedef __attribute__((ext_vector_type(8))) short bf16x8;

static __device__ inline unsigned short f2bf(float f) {
    union { float f; unsigned int u; } a;
    a.f = f;
    unsigned int u = a.u;
    return (unsigned short)((u + 0x7FFFu + ((u >> 16) & 1u)) >> 16);  // RNE
}
static __device__ inline float bf2f(unsigned short h) {
    union { unsigned int u; float f; } a;
    a.u = ((unsigned int)h) << 16;
    return a.f;
}

__global__ __launch_bounds__(256) void cast_f32_bf16(const float* __restrict__ in,
                                                     unsigned short* __restrict__ out, int n4) {
    int i = blockIdx.x * 256 + threadIdx.x;
    if (i < n4) {
        float4 v = ((const float4*)in)[i];
        ushort4 o;
        o.x = f2bf(v.x); o.y = f2bf(v.y); o.z = f2bf(v.z); o.w = f2bf(v.w);
        ((ushort4*)out)[i] = o;
    }
}

// C[M,N] = A[M,K] (bf16 row-major) @ Bm[N,K]^T (bf16 row-major).
// 4 waves (2x2), wave tile 64x64 (4x4 mfma 16x16x32), block tile 128x128,
// BK=32, LDS staging via global_load_lds width=16 (m97 structure).
template <bool BF16OUT>
__global__ __launch_bounds__(256) void gemm_bt(const short* __restrict__ A,
                                               const short* __restrict__ Bm,
                                               void* __restrict__ Cout,
                                               int M, int N, int K) {
    __shared__ short lds[8192];  // A tile: shorts [0,4096), B tile: [4096,8192)
    const int lane = threadIdx.x & 63;
    const int wave = threadIdx.x >> 6;
    const int wr = wave >> 1, wc = wave & 1;
    const int bm = blockIdx.y * 128, bn = blockIdx.x * 128;

    // staging map: chunk = 16 rows x 32 cols = 1024 B; lane -> (row, 8-col block)
    const int r0 = lane >> 2;   // 0..15
    const int cb = lane & 3;    // 0..3

    const int m_base = wr * 64 + (lane & 15);
    const int n_base = wc * 64 + (lane & 15);
    const int k_off = (lane >> 4) * 8;

    f32x4 acc[4][4] = {};

    for (int k0 = 0; k0 < K; k0 += 32) {
#pragma unroll
        for (int cc = 0; cc < 2; ++cc) {
            const int chunk = wave * 2 + cc;
            const int row = chunk * 16 + r0;
            const short* ga = A + (size_t)(bm + row) * K + k0 + cb * 8;
            const short* gb = Bm + (size_t)(bn + row) * K + k0 + cb * 8;
            __builtin_amdgcn_global_load_lds(
                (const __attribute__((address_space(1))) void*)ga,
                (__attribute__((address_space(3))) void*)&lds[chunk * 512], 16, 0, 0);
            __builtin_amdgcn_global_load_lds(
                (const __attribute__((address_space(1))) void*)gb,
                (__attribute__((address_space(3))) void*)&lds[4096 + chunk * 512], 16, 0, 0);
        }
        __syncthreads();
        bf16x8 a[4], b[4];
#pragma unroll
        for (int i = 0; i < 4; ++i)
            a[i] = *(const bf16x8*)&lds[(m_base + i * 16) * 32 + k_off];
#pragma unroll
        for (int j = 0; j < 4; ++j)
            b[j] = *(const bf16x8*)&lds[4096 + (n_base + j * 16) * 32 + k_off];
#pragma unroll
        for (int i = 0; i < 4; ++i)
#pragma unroll
            for (int j = 0; j < 4; ++j)
                acc[i][j] = __builtin_amdgcn_mfma_f32_16x16x32_bf16(a[i], b[j], acc[i][j], 0, 0, 0);
        __syncthreads();
    }

    const int row0 = (lane >> 4) * 4;
#pragma unroll
    for (int i = 0; i < 4; ++i) {
#pragma unroll
        for (int j = 0; j < 4; ++j) {
            const int col = bn + wc * 64 + j * 16 + (lane & 15);
#pragma unroll
            for (int r = 0; r < 4; ++r) {
                const size_t row = bm + wr * 64 + i * 16 + row0 + r;
                if constexpr (BF16OUT)
                    ((unsigned short*)Cout)[row * N + col] = f2bf(acc[i][j][r]);
                else
                    ((float*)Cout)[row * N + col] = acc[i][j][r];
            }
        }
    }
}

// Pass 1: per-chunk complex sums of w_t = v_t * e^{i t f}, incremental rotor.
__global__ __launch_bounds__(256) void scan_pass1(const unsigned short* __restrict__ v,
                                                  const float* __restrict__ freqs,
                                                  float* __restrict__ csum) {
    const int d = blockIdx.x * 256 + threadIdx.x;
    const int chunk = blockIdx.y;
    const int b = blockIdx.z;
    const float f = freqs[d];
    const int t0 = chunk * CS_;
    float s, c, sf, cf;
    sincosf((float)t0 * f, &s, &c);
    sincosf(f, &sf, &cf);
    float ar = 0.f, ai = 0.f;
    const unsigned short* vp = v + ((size_t)b * T_ + t0) * D_ + d;
    for (int t = 0; t < CS_; ++t) {
        float w = bf2f(*vp); vp += D_;
        ar = fmaf(w, c, ar); ai = fmaf(w, s, ai);
        float c2 = c * cf - s * sf;
        float s2 = s * cf + c * sf;
        c = c2; s = s2;
    }
    const size_t idx = (((size_t)b * NCHUNK_ + chunk) * D_ + d) * 2;
    csum[idx] = ar; csum[idx + 1] = ai;
}

// Pass 2: exclusive prefix of chunk sums per (b,d), batched loads (latency).
__global__ __launch_bounds__(256) void scan_pass2(float* __restrict__ csum) {
    const int g = blockIdx.x * 256 + threadIdx.x;  // 0 .. B*D-1
    const int b = g / D_;
    const int d = g % D_;
    float2* cs = (float2*)csum;
    const size_t base = (size_t)b * NCHUNK_ * D_ + d;
    float pr = 0.f, pi = 0.f;
    for (int cc = 0; cc < NCHUNK_; cc += 16) {
        float2 buf[16];
#pragma unroll
        for (int k = 0; k < 16; ++k) buf[k] = cs[base + (size_t)(cc + k) * D_];
#pragma unroll
        for (int k = 0; k < 16; ++k) {
            float r = buf[k].x, im = buf[k].y;
            buf[k] = make_float2(pr, pi);
            pr += r; pi += im;
        }
#pragma unroll
        for (int k = 0; k < 16; ++k) cs[base + (size_t)(cc + k) * D_] = buf[k];
    }
}

// Pass 3: replay chunk with prefix offset; retrieved = Re(mt * conj(rotor)) -> bf16
__global__ __launch_bounds__(256) void scan_pass3(const unsigned short* __restrict__ v,
                                                  const float* __restrict__ freqs,
                                                  const float* __restrict__ csum,
                                                  unsigned short* __restrict__ ret) {
    const int d = blockIdx.x * 256 + threadIdx.x;
    const int chunk = blockIdx.y;
    const int b = blockIdx.z;
    const float f = freqs[d];
    const size_t cidx = (((size_t)b * NCHUNK_ + chunk) * D_ + d) * 2;
    float ar = csum[cidx], ai = csum[cidx + 1];
    const int t0 = chunk * CS_;
    float s, c, sf, cf;
    sincosf((float)t0 * f, &s, &c);
    sincosf(f, &sf, &cf);
    const unsigned short* vp = v + ((size_t)b * T_ + t0) * D_ + d;
    unsigned short* rp = ret + ((size_t)b * T_ + t0) * D_ + d;
    for (int t = 0; t < CS_; ++t) {
        float w = bf2f(*vp); vp += D_;
        ar = fmaf(w, c, ar); ai = fmaf(w, s, ai);
        *rp = f2bf(ar * c + ai * s);  // Re(mt * (cos - i sin))
        rp += D_;
        float c2 = c * cf - s * sf;
        float s2 = s * cf + c * sf;
        c = c2; s = s2;
    }
}

extern "C" void kernel_launch(void* const* d_in, const int* in_sizes, int n_in,
                              void* d_out, int out_size, void* d_ws, size_t ws_size,
                              hipStream_t stream) {
    const float* x     = (const float*)d_in[0];
    // d_in[1] = Wk (dead in reference)
    const float* Wv    = (const float*)d_in[2];
    const float* Wo    = (const float*)d_in[3];
    const float* freqs = (const float*)d_in[4];
    float* out = (float*)d_out;

    char* ws = (char*)d_ws;
    unsigned short* x_bf  = (unsigned short*)ws;                 // 33,554,432 B
    unsigned short* Wv_bf = (unsigned short*)(ws + 33554432);    //  2,097,152 B
    unsigned short* Wo_bf = (unsigned short*)(ws + 35651584);    //  2,097,152 B
    unsigned short* ret   = (unsigned short*)(ws + 37748736);    // 33,554,432 B
    float*          csum  = (float*)(ws + 71303168);             //  2,097,152 B (B*128*D*2*4)
    // v (bf16) lives in d_out's first half; dead before GEMM2 overwrites d_out.
    unsigned short* v_bf = (unsigned short*)d_out;

    // 1. casts
    cast_f32_bf16<<<(BT_ * D_ / 4 + 255) / 256, 256, 0, stream>>>(x, x_bf, BT_ * D_ / 4);
    cast_f32_bf16<<<(D_ * D_ / 4 + 255) / 256, 256, 0, stream>>>(Wv, Wv_bf, D_ * D_ / 4);
    cast_f32_bf16<<<(D_ * D_ / 4 + 255) / 256, 256, 0, stream>>>(Wo, Wo_bf, D_ * D_ / 4);

    // 2. v = x @ Wv^T  (bf16 out)
    gemm_bt<true><<<dim3(D_ / 128, BT_ / 128), 256, 0, stream>>>(
        (const short*)x_bf, (const short*)Wv_bf, (void*)v_bf, BT_, D_, D_);

    // 3. blocked rotor scan
    dim3 sgrid(D_ / 256, NCHUNK_, B_);
    scan_pass1<<<sgrid, 256, 0, stream>>>(v_bf, freqs, csum);
    scan_pass2<<<(B_ * D_) / 256, 256, 0, stream>>>(csum);
    scan_pass3<<<sgrid, 256, 0, stream>>>(v_bf, freqs, csum, ret);

    // 4. out = retrieved @ Wo^T (fp32 out)
    gemm_bt<false><<<dim3(D_ / 128, BT_ / 128), 256, 0, stream>>>(
        (const short*)ret, (const short*)Wo_bf, (void*)out, BT_, D_, D_);
}

// Round 3
// 263.365 us; speedup vs baseline: 1.6985x; 1.0593x over previous
//
#include <hip/hip_runtime.h>
#include <hip/hip_bf16.h>

// HoloAttention: out = (Re(cumsum_t(x@Wv^T * e^{i t f}) * e^{-i t f})) @ Wo^T
// (k-projection in reference is dead code — skipped.)
//
// R3: XCD-swizzled GEMM grid (all 8 N-blocks of an M-tile on one XCD -> A-tile
// L2 reuse), 2-d-per-thread vectorized scan passes, fused cast kernel.

#define B_  2
#define T_  8192
#define D_  1024
#define BT_ 16384
#define CS_ 64
#define NCHUNK_ 128

typedef __attribute__((ext_vector_type(4))) float f32x4;
typedef __attribute__((ext_vector_type(8))) short bf16x8;

static __device__ inline unsigned short f2bf(float f) {
    union { float f; unsigned int u; } a;
    a.f = f;
    unsigned int u = a.u;
    return (unsigned short)((u + 0x7FFFu + ((u >> 16) & 1u)) >> 16);  // RNE
}
static __device__ inline float bf2f(unsigned short h) {
    union { unsigned int u; float f; } a;
    a.u = ((unsigned int)h) << 16;
    return a.f;
}

// One fused cast: x (4194304 float4) | Wv (262144) | Wo (262144)
__global__ __launch_bounds__(256) void cast_all(const float* __restrict__ x,
                                                const float* __restrict__ Wv,
                                                const float* __restrict__ Wo,
                                                unsigned short* __restrict__ xb,
                                                unsigned short* __restrict__ wvb,
                                                unsigned short* __restrict__ wob) {
    const int nx = BT_ * D_ / 4;
    const int nw = D_ * D_ / 4;
    int i = blockIdx.x * 256 + threadIdx.x;
    const float4* src;
    unsigned short* dst;
    int j;
    if (i < nx)            { src = (const float4*)x;  dst = xb;  j = i; }
    else if (i < nx + nw)  { src = (const float4*)Wv; dst = wvb; j = i - nx; }
    else                   { src = (const float4*)Wo; dst = wob; j = i - nx - nw; }
    float4 v = src[j];
    ushort4 o;
    o.x = f2bf(v.x); o.y = f2bf(v.y); o.z = f2bf(v.z); o.w = f2bf(v.w);
    ((ushort4*)dst)[j] = o;
}

// C[M,N] = A[M,K] (bf16 row-major) @ Bm[N,K]^T (bf16 row-major).
// 4 waves (2x2), wave tile 64x64 (4x4 mfma 16x16x32), block tile 128x128,
// BK=32, LDS staging via global_load_lds width=16 (m97 structure).
// 1-D grid with XCD swizzle: id&7 -> XCD (round-robin dispatch heuristic);
// the 8 N-blocks sharing an M-tile get consecutive slots on ONE XCD so the
// A-tile is fetched into that XCD's L2 once.
template <bool BF16OUT>
__global__ __launch_bounds__(256) void gemm_bt(const short* __restrict__ A,
                                               const short* __restrict__ Bm,
                                               void* __restrict__ Cout,
                                               int M, int N, int K) {
    __shared__ short lds[8192];  // A tile: shorts [0,4096), B tile: [4096,8192)
    const int lane = threadIdx.x & 63;
    const int wave = threadIdx.x >> 6;
    const int wr = wave >> 1, wc = wave & 1;

    const int nb = N >> 7;              // N-blocks (8)
    const int id = blockIdx.x;
    const int xcd = id & 7;
    const int slot = id >> 3;
    const int bn = (slot % nb) * 128;
    const int bm = (xcd * ((M >> 7) >> 3) + slot / nb) * 128;

    // staging map: chunk = 16 rows x 32 cols = 1024 B; lane -> (row, 8-col block)
    const int r0 = lane >> 2;   // 0..15
    const int cb = lane & 3;    // 0..3

    const int m_base = wr * 64 + (lane & 15);
    const int n_base = wc * 64 + (lane & 15);
    const int k_off = (lane >> 4) * 8;

    f32x4 acc[4][4] = {};

    for (int k0 = 0; k0 < K; k0 += 32) {
#pragma unroll
        for (int cc = 0; cc < 2; ++cc) {
            const int chunk = wave * 2 + cc;
            const int row = chunk * 16 + r0;
            const short* ga = A + (size_t)(bm + row) * K + k0 + cb * 8;
            const short* gb = Bm + (size_t)(bn + row) * K + k0 + cb * 8;
            __builtin_amdgcn_global_load_lds(
                (const __attribute__((address_space(1))) void*)ga,
                (__attribute__((address_space(3))) void*)&lds[chunk * 512], 16, 0, 0);
            __builtin_amdgcn_global_load_lds(
                (const __attribute__((address_space(1))) void*)gb,
                (__attribute__((address_space(3))) void*)&lds[4096 + chunk * 512], 16, 0, 0);
        }
        __syncthreads();
        bf16x8 a[4], b[4];
#pragma unroll
        for (int i = 0; i < 4; ++i)
            a[i] = *(const bf16x8*)&lds[(m_base + i * 16) * 32 + k_off];
#pragma unroll
        for (int j = 0; j < 4; ++j)
            b[j] = *(const bf16x8*)&lds[4096 + (n_base + j * 16) * 32 + k_off];
#pragma unroll
        for (int i = 0; i < 4; ++i)
#pragma unroll
            for (int j = 0; j < 4; ++j)
                acc[i][j] = __builtin_amdgcn_mfma_f32_16x16x32_bf16(a[i], b[j], acc[i][j], 0, 0, 0);
        __syncthreads();
    }

    const int row0 = (lane >> 4) * 4;
#pragma unroll
    for (int i = 0; i < 4; ++i) {
#pragma unroll
        for (int j = 0; j < 4; ++j) {
            const int col = bn + wc * 64 + j * 16 + (lane & 15);
#pragma unroll
            for (int r = 0; r < 4; ++r) {
                const size_t row = bm + wr * 64 + i * 16 + row0 + r;
                if constexpr (BF16OUT)
                    ((unsigned short*)Cout)[row * N + col] = f2bf(acc[i][j][r]);
                else
                    ((float*)Cout)[row * N + col] = acc[i][j][r];
            }
        }
    }
}

// Pass 1: per-chunk complex sums of w_t = v_t * e^{i t f}; 2 d's per thread.
__global__ __launch_bounds__(256) void scan_pass1(const unsigned short* __restrict__ v,
                                                  const float* __restrict__ freqs,
                                                  float* __restrict__ csum) {
    const int d0 = (blockIdx.x * 256 + threadIdx.x) * 2;
    const int chunk = blockIdx.y;
    const int b = blockIdx.z;
    const float2 f2 = *(const float2*)(freqs + d0);
    const int t0 = chunk * CS_;
    float s0, c0, s1, c1, sf0, cf0, sf1, cf1;
    sincosf((float)t0 * f2.x, &s0, &c0);
    sincosf((float)t0 * f2.y, &s1, &c1);
    sincosf(f2.x, &sf0, &cf0);
    sincosf(f2.y, &sf1, &cf1);
    float ar0 = 0.f, ai0 = 0.f, ar1 = 0.f, ai1 = 0.f;
    const unsigned int* vp = (const unsigned int*)(v + ((size_t)b * T_ + t0) * D_ + d0);
    for (int t = 0; t < CS_; ++t) {
        unsigned int w2 = *vp; vp += D_ / 2;
        float w0 = bf2f((unsigned short)w2);
        float w1 = bf2f((unsigned short)(w2 >> 16));
        ar0 = fmaf(w0, c0, ar0); ai0 = fmaf(w0, s0, ai0);
        ar1 = fmaf(w1, c1, ar1); ai1 = fmaf(w1, s1, ai1);
        float nc0 = c0 * cf0 - s0 * sf0, ns0 = s0 * cf0 + c0 * sf0;
        float nc1 = c1 * cf1 - s1 * sf1, ns1 = s1 * cf1 + c1 * sf1;
        c0 = nc0; s0 = ns0; c1 = nc1; s1 = ns1;
    }
    float4 o; o.x = ar0; o.y = ai0; o.z = ar1; o.w = ai1;
    *(float4*)(csum + (((size_t)b * NCHUNK_ + chunk) * D_ + d0) * 2) = o;
}

// Pass 2: exclusive prefix of chunk sums per (b,d), batched loads (latency).
__global__ __launch_bounds__(256) void scan_pass2(float* __restrict__ csum) {
    const int g = blockIdx.x * 256 + threadIdx.x;  // 0 .. B*D-1
    const int b = g / D_;
    const int d = g % D_;
    float2* cs = (float2*)csum;
    const size_t base = (size_t)b * NCHUNK_ * D_ + d;
    float pr = 0.f, pi = 0.f;
    for (int cc = 0; cc < NCHUNK_; cc += 16) {
        float2 buf[16];
#pragma unroll
        for (int k = 0; k < 16; ++k) buf[k] = cs[base + (size_t)(cc + k) * D_];
#pragma unroll
        for (int k = 0; k < 16; ++k) {
            float r = buf[k].x, im = buf[k].y;
            buf[k] = make_float2(pr, pi);
            pr += r; pi += im;
        }
#pragma unroll
        for (int k = 0; k < 16; ++k) cs[base + (size_t)(cc + k) * D_] = buf[k];
    }
}

// Pass 3: replay chunk; retrieved = Re(mt * conj(rotor)) -> bf16; 2 d's/thread.
__global__ __launch_bounds__(256) void scan_pass3(const unsigned short* __restrict__ v,
                                                  const float* __restrict__ freqs,
                                                  const float* __restrict__ csum,
                                                  unsigned short* __restrict__ ret) {
    const int d0 = (blockIdx.x * 256 + threadIdx.x) * 2;
    const int chunk = blockIdx.y;
    const int b = blockIdx.z;
    const float2 f2 = *(const float2*)(freqs + d0);
    const float4 cs4 = *(const float4*)(csum + (((size_t)b * NCHUNK_ + chunk) * D_ + d0) * 2);
    float ar0 = cs4.x, ai0 = cs4.y, ar1 = cs4.z, ai1 = cs4.w;
    const int t0 = chunk * CS_;
    float s0, c0, s1, c1, sf0, cf0, sf1, cf1;
    sincosf((float)t0 * f2.x, &s0, &c0);
    sincosf((float)t0 * f2.y, &s1, &c1);
    sincosf(f2.x, &sf0, &cf0);
    sincosf(f2.y, &sf1, &cf1);
    const unsigned int* vp = (const unsigned int*)(v + ((size_t)b * T_ + t0) * D_ + d0);
    unsigned int* rp = (unsigned int*)(ret + ((size_t)b * T_ + t0) * D_ + d0);
    for (int t = 0; t < CS_; ++t) {
        unsigned int w2 = *vp; vp += D_ / 2;
        float w0 = bf2f((unsigned short)w2);
        float w1 = bf2f((unsigned short)(w2 >> 16));
        ar0 = fmaf(w0, c0, ar0); ai0 = fmaf(w0, s0, ai0);
        ar1 = fmaf(w1, c1, ar1); ai1 = fmaf(w1, s1, ai1);
        float o0 = ar0 * c0 + ai0 * s0;   // Re(mt * (cos - i sin))
        float o1 = ar1 * c1 + ai1 * s1;
        *rp = (unsigned int)f2bf(o0) | ((unsigned int)f2bf(o1) << 16);
        rp += D_ / 2;
        float nc0 = c0 * cf0 - s0 * sf0, ns0 = s0 * cf0 + c0 * sf0;
        float nc1 = c1 * cf1 - s1 * sf1, ns1 = s1 * cf1 + c1 * sf1;
        c0 = nc0; s0 = ns0; c1 = nc1; s1 = ns1;
    }
}

extern "C" void kernel_launch(void* const* d_in, const int* in_sizes, int n_in,
                              void* d_out, int out_size, void* d_ws, size_t ws_size,
                              hipStream_t stream) {
    const float* x     = (const float*)d_in[0];
    // d_in[1] = Wk (dead in reference)
    const float* Wv    = (const float*)d_in[2];
    const float* Wo    = (const float*)d_in[3];
    const float* freqs = (const float*)d_in[4];
    float* out = (float*)d_out;

    char* ws = (char*)d_ws;
    unsigned short* x_bf  = (unsigned short*)ws;                 // 33,554,432 B
    unsigned short* Wv_bf = (unsigned short*)(ws + 33554432);    //  2,097,152 B
    unsigned short* Wo_bf = (unsigned short*)(ws + 35651584);    //  2,097,152 B
    unsigned short* ret   = (unsigned short*)(ws + 37748736);    // 33,554,432 B
    float*          csum  = (float*)(ws + 71303168);             //  2,097,152 B
    // v (bf16) lives in d_out's first half; dead before GEMM2 overwrites d_out.
    unsigned short* v_bf = (unsigned short*)d_out;

    // 1. fused casts (x | Wv | Wo)
    cast_all<<<(BT_ * D_ / 4 + 2 * D_ * D_ / 4) / 256, 256, 0, stream>>>(
        x, Wv, Wo, x_bf, Wv_bf, Wo_bf);

    // 2. v = x @ Wv^T  (bf16 out), XCD-swizzled 1-D grid
    gemm_bt<true><<<(BT_ / 128) * (D_ / 128), 256, 0, stream>>>(
        (const short*)x_bf, (const short*)Wv_bf, (void*)v_bf, BT_, D_, D_);

    // 3. blocked rotor scan
    dim3 sgrid(D_ / 512, NCHUNK_, B_);
    scan_pass1<<<sgrid, 256, 0, stream>>>(v_bf, freqs, csum);
    scan_pass2<<<(B_ * D_) / 256, 256, 0, stream>>>(csum);
    scan_pass3<<<sgrid, 256, 0, stream>>>(v_bf, freqs, csum, ret);

    // 4. out = retrieved @ Wo^T (fp32 out), XCD-swizzled 1-D grid
    gemm_bt<false><<<(BT_ / 128) * (D_ / 128), 256, 0, stream>>>(
        (const short*)ret, (const short*)Wo_bf, (void*)out, BT_, D_, D_);
}